// Round 9
// baseline (1985.348 us; speedup 1.0000x reference)
//
#include <hip/hip_runtime.h>
#include <hip/hip_bf16.h>

// RadarTpaLSTM: 3-layer LSTM (B=1024,T=64,HD=512) + conv-attention head.
// Round 13: MFMA-ize k1_attn. LSTM stage config frozen at R12's verified
// 1968us: 64x128 tiles, 512thr/8wave blocks, 3 blocks/CU (24 waves/CU).
//  - k1_attn v2: conv einsum C[c,f] = sum_t kC[c,t]*H[t,f] as MFMA GEMM
//    (M=64,N=512,K=64 per b). A = convW natively [c][t] (prep_kc, no
//    transpose). B = relu(H) transposed into LDS Ht[f][t] with XOR chunk
//    swizzle (chunk ^= (f&7)^((f>>3)&7)): 2-way (free) on both u32
//    transpose-writes (lane map spreads f8lo x t2lo) and ds_read_b128
//    fragment reads. Attention (alpha, v) in-register via shfl_xor;
//    vbuf/k3_out flow unchanged.
//  - prep_x (bf16 x), k3_out folded via prep_fw: as before.
// Fragment layout (single source of truth, used by prep_w AND lstm_stage):
//   B-tile (128 perm-cols x 64 k) per (layer,nt,ch): frag fb = nb*2+kk,
//   elem (fb, lane, j) = W[permcol = nt*128 + nb*16 + (lane&15)]
//                         [k = ch*64 + kk*32 + (lane>>4)*8 + j]
//   perm-col win = nb*16+c: half=nb>>2, gate=nb&3, j_hid = nt*32+half*16+c,
//   orig row = gate*512 + j_hid.  (gate order i,f,g,o)
//   A-tile (64 rows x 64 k): frag fa = mb*2+kk (mb=0..3),
//   elem = A[row = b0 + mb*16 + (lane&15)][k = kof + kk*32 + (lane>>4)*8 + j]

typedef short v8s __attribute__((ext_vector_type(8)));
typedef float v4f __attribute__((ext_vector_type(4)));
typedef __hip_bfloat16 bf16;

#define B_   1024
#define T_   64
#define D_   512
#define HD_  512

__device__ __forceinline__ float sigm(float v) { return 1.0f / (1.0f + __expf(-v)); }
__device__ __forceinline__ float tanh_(float v) { return 2.0f / (1.0f + __expf(-2.0f * v)) - 1.0f; }
__device__ __forceinline__ float b2f(bf16 v) { return __bfloat162float(v); }
__device__ __forceinline__ float bu2f(ushort u) {
  union { unsigned i; float f; } x; x.i = ((unsigned)u) << 16; return x.f;
}

// load 8 fp32, round to bf16, store 16B
__device__ __forceinline__ void cvt_store8(ushort* dst, const float* src) {
  float4 a = *(const float4*)src;
  float4 b = *(const float4*)(src + 4);
  bf16 h[8] = {__float2bfloat16(a.x), __float2bfloat16(a.y),
               __float2bfloat16(a.z), __float2bfloat16(a.w),
               __float2bfloat16(b.x), __float2bfloat16(b.y),
               __float2bfloat16(b.z), __float2bfloat16(b.w)};
  *(uint4*)dst = *(const uint4*)h;
}

// async global->LDS, 16B per lane; lds base must be wave-uniform.
__device__ __forceinline__ void glds16(const bf16* g, ushort* l) {
  __builtin_amdgcn_global_load_lds(
      (const __attribute__((address_space(1))) void*)g,
      (__attribute__((address_space(3))) void*)l, 16, 0, 0);
}

// ---------------- workspace layout ----------------
constexpr size_t SZ_YS = (size_t)T_ * B_ * HD_ * 2;     // bf16 [T][B][HD] layer-2 h
constexpr size_t SZ_HB = (size_t)2 * 2 * B_ * HD_ * 2;  // h layers 0/1, dbuf, bf16
constexpr size_t SZ_CB = (size_t)3 * B_ * HD_ * 4;      // c fp32, 3 layers
constexpr size_t SZ_ZP = (size_t)B_ * HD_ * 2;          // zero page (bf16)
constexpr size_t SZ_WV = (size_t)B_ * 64 * 4;           // w = htt@lin1^T fp32
constexpr size_t SZ_VB = (size_t)B_ * 64 * 4;           // v accumulator fp32
constexpr size_t SZ_WB = (size_t)3 * 2048 * 1024 * 2;   // frag-ordered bf16 weights
constexpr size_t SZ_KC = (size_t)64 * 64 * 2;           // conv kernel [c][t] bf16
constexpr size_t SZ_FW = (size_t)640 * 4;               // fused outW@lin2W (+bias)
constexpr size_t SZ_XB = (size_t)T_ * B_ * D_ * 2;      // x as bf16 [T][B][D]
constexpr size_t O_YS = 0;
constexpr size_t O_HB = O_YS + SZ_YS;
constexpr size_t O_CB = O_HB + SZ_HB;
constexpr size_t O_ZP = O_CB + SZ_CB;
constexpr size_t O_WV = O_ZP + SZ_ZP;
constexpr size_t O_VB = O_WV + SZ_WV;
constexpr size_t O_WB = O_VB + SZ_VB;
constexpr size_t O_KC = O_WB + SZ_WB;
constexpr size_t O_FW = O_KC + SZ_KC;
constexpr size_t O_XB = O_FW + SZ_FW;

// ---------------- prep: weights -> fragment-ordered bf16 ----------------
__global__ __launch_bounds__(256) void prep_w(const float* __restrict__ Wih,
                                              const float* __restrict__ Whh,
                                              bf16* __restrict__ Wbuf) {
  int tf = blockIdx.x * 256 + threadIdx.x;  // [0, 786432), 8 elems each
  int group = tf >> 10;                     // (layer, nt, ch)
  int layer = group >> 8, rem = group & 255;
  int nt = rem >> 4, ch = rem & 15;
  int li = tf & 1023;
  int frag = li >> 6, lane = li & 63;
  int nb = frag >> 1, kk = frag & 1;
  int c = lane & 15, q = lane >> 4;
  int half = nb >> 2, gate = nb & 3;
  int j = nt * 32 + half * 16 + c;
  int R = gate * 512 + j;
  int k = (ch & 7) * 64 + kk * 32 + q * 8;
  const float* src = ((ch < 8) ? Wih : Whh) + ((size_t)layer * 2048 + R) * 512 + k;
  cvt_store8((ushort*)(Wbuf + (size_t)tf * 8), src);
}

// x fp32 [B][T][D] -> bf16 [T][B][D] (one-time; off the recurrent path)
__global__ __launch_bounds__(256) void prep_x(const float* __restrict__ x,
                                              bf16* __restrict__ xb) {
  int idx = blockIdx.x * 256 + threadIdx.x;  // < 4194304, 8 elems each
  int d8 = idx & 63;
  int bt = idx >> 6;
  int b = bt & 1023, t = bt >> 10;
  cvt_store8((ushort*)(xb + ((size_t)t * B_ + b) * D_ + d8 * 8),
             x + ((size_t)b * T_ + t) * D_ + d8 * 8);
}

// conv kernel, native layout: kC[c][t] = convW[c][t] bf16 (t=63 pad zero)
__global__ __launch_bounds__(256) void prep_kc(const float* __restrict__ convW,
                                               bf16* __restrict__ kC) {
  int idx = blockIdx.x * 256 + threadIdx.x;  // < 4096
  int c = idx >> 6, t = idx & 63;
  kC[idx] = __float2bfloat16(t < 63 ? convW[c * 63 + t] : 0.f);
}

// fused output weights: fw[k] = sum_j outW[j]*lin2W[j][k] (k<576);
// fw[576] = outW.lin2b + outb.
__global__ __launch_bounds__(64) void prep_fw(const float* __restrict__ lin2W,
                                              const float* __restrict__ lin2b,
                                              const float* __restrict__ outW,
                                              const float* __restrict__ outb,
                                              float* __restrict__ fw) {
  const int blk = blockIdx.x, tid = threadIdx.x;
  if (blk < 9) {
    const int k = blk * 64 + tid;
    float a = 0.f;
    for (int j = 0; j < 512; ++j) a += outW[j] * lin2W[(size_t)j * 576 + k];
    fw[k] = a;
  } else {
    float a = 0.f;
    for (int j = tid; j < 512; j += 64) a += outW[j] * lin2b[j];
    for (int m = 1; m < 64; m <<= 1) a += __shfl_xor(a, m);
    if (tid == 0) fw[576] = a + outb[0];
  }
}

// ---------------- LSTM stage kernel (64x128 tiles, 8-wave blocks) ----------
// (R12-verified config, frozen.)
__global__ __launch_bounds__(512, 6) void lstm_stage(
    const bf16* __restrict__ xb, const bf16* __restrict__ Wbuf,
    const float* __restrict__ bih, const float* __restrict__ bhh,
    bf16* __restrict__ ys, bf16* __restrict__ hbuf, float* __restrict__ cbuf,
    const bf16* __restrict__ zp, int s, int llo) {
  __shared__ ushort As[2][4096];   // 8 frags x 512
  __shared__ ushort Bs[2][8192];   // 16 frags x 512

  const int layer = llo + (blockIdx.x >> 8);
  const int tile = blockIdx.x & 255;
  const int t = s - layer;
  const int mt = tile >> 4, nt = tile & 15;
  const int b0 = mt << 6;
  const int p = s & 1;

  bf16* hw = (layer < 2) ? hbuf + ((size_t)p * 2 + layer) * (B_ * HD_)
                         : ys + (size_t)t * (B_ * HD_);
  const bf16* srcA0 = (layer == 0)
      ? xb + (size_t)t * (B_ * D_)
      : hbuf + ((size_t)(p ^ 1) * 2 + (layer - 1)) * (B_ * HD_);
  const bf16* srcA1 = (layer < 2)
      ? hbuf + ((size_t)(p ^ 1) * 2 + layer) * (B_ * HD_)
      : ((t == 0) ? zp : ys + (size_t)(t - 1) * (B_ * HD_));
  const bf16* Wb = Wbuf + ((size_t)layer * 16 + nt) * 16 * 8192;

  const int tid = threadIdx.x, lane = tid & 63, w = tid >> 6;
  const int c = lane & 15, q = lane >> 4;
  const int wm = w >> 1, wn = w & 1;

  v4f acc[4];
#pragma unroll
  for (int ni = 0; ni < 4; ++ni) acc[ni] = v4f{0.f, 0.f, 0.f, 0.f};

  auto STAGE = [&](int ch, int pb) {
    const int kof = (ch & 7) * 64;
    const bf16* wsrc = Wb + (size_t)ch * 8192;
    const bf16* sA = (ch < 8) ? srcA0 : srcA1;
#pragma unroll
    for (int i = 0; i < 3; ++i) {
      int idx = w * 3 + i;  // 0..23: 0-15 = B frags, 16-23 = A frags
      if (idx < 16) {
        glds16(wsrc + idx * 512 + lane * 8, &Bs[pb][idx * 512]);
      } else {
        int f = idx - 16, mb = f >> 1, k2 = f & 1;
        glds16(sA + (size_t)(b0 + mb * 16 + c) * HD_ + kof + k2 * 32 + q * 8,
               &As[pb][f * 512]);
      }
    }
  };

  STAGE(0, 0);
  __syncthreads();

  for (int ch = 0; ch < 16; ++ch) {
    const int pb = ch & 1;
    if (ch < 15) STAGE(ch + 1, pb ^ 1);  // in flight across the MFMA block
    __builtin_amdgcn_s_setprio(1);
#pragma unroll
    for (int kk = 0; kk < 2; ++kk) {
      v8s af = *(const v8s*)&As[pb][(wm * 2 + kk) * 512 + lane * 8];
#pragma unroll
      for (int ni = 0; ni < 4; ++ni) {
        v8s bfr = *(const v8s*)&Bs[pb][((wn * 4 + ni) * 2 + kk) * 512 + lane * 8];
        acc[ni] = __builtin_amdgcn_mfma_f32_16x16x32_bf16(af, bfr, acc[ni], 0, 0, 0);
      }
    }
    __builtin_amdgcn_s_setprio(0);
    __syncthreads();  // drains this wave's glds16 (vmcnt) + ds_reads (lgkm)
  }

  float* cl = cbuf + (size_t)layer * (B_ * HD_);
  const size_t bb = (size_t)layer * 2048;
  const int j = nt * 32 + wn * 16 + c;
  float bsum[4];
#pragma unroll
  for (int g4 = 0; g4 < 4; ++g4)
    bsum[g4] = bih[bb + g4 * 512 + j] + bhh[bb + g4 * 512 + j];
#pragma unroll
  for (int r = 0; r < 4; ++r) {
    const int b = b0 + wm * 16 + q * 4 + r;
    float iv = acc[0][r] + bsum[0];
    float fv = acc[1][r] + bsum[1];
    float gv = acc[2][r] + bsum[2];
    float ov = acc[3][r] + bsum[3];
    size_t off = (size_t)b * HD_ + j;
    float cprev = cl[off];
    float cn = sigm(fv) * cprev + sigm(iv) * tanh_(gv);
    float hn = sigm(ov) * tanh_(cn);
    cl[off] = cn;
    hw[off] = __float2bfloat16(hn);
  }
}

// ---------------- epilogue: w = htt @ lin1^T + lin1b ----------------
__global__ __launch_bounds__(64) void k0_lin1(const bf16* __restrict__ ys,
                                              const float* __restrict__ lin1W,
                                              const float* __restrict__ lin1b,
                                              float* __restrict__ wv) {
  __shared__ float htt[HD_];
  const int b = blockIdx.x, tid = threadIdx.x;
  for (int i = tid; i < HD_; i += 64)
    htt[i] = b2f(ys[((size_t)(T_ - 1) * B_ + b) * HD_ + i]);
  __syncthreads();
  float a = lin1b[tid];
  const float* wr = lin1W + (size_t)tid * HD_;
  for (int k = 0; k < HD_; k += 4) {
    float4 w4 = *(const float4*)(wr + k);
    a += htt[k] * w4.x + htt[k + 1] * w4.y + htt[k + 2] * w4.z + htt[k + 3] * w4.w;
  }
  wv[(size_t)b * 64 + tid] = a;
}

// ---------------- epilogue: conv einsum (MFMA) + attention (per b) ---------
// 256 thr / 4 waves. Phase 1: relu(H) -> LDS Ht[f][t] bf16, transposed,
// XOR-swizzled: byte(f,t) = f*128 + (((t>>3)^(f&7)^((f>>3)&7))&7)*16
// + (t&7)*2. Lane map spreads (f8lo x t2lo) -> 2-way banks on writes/reads.
// Phase 2: per wave (f-range w*128): C[c,f] = sum_t kC[c,t]*Ht[f,t] via
// 64 MFMA 16x16x32 (acc[4][8]); then in-register attention:
//   i = c*8 + (f>>6), j = f&63;  s[i] = sum_j Cr*wv[j] (4x shfl_xor over
//   lane&15);  alpha = sigm(s);  v[j] = sum_i alpha*Cr (xor16/32);
//   atomicAdd vbuf (k3_out unchanged).
__global__ __launch_bounds__(256) void k1_attn(const bf16* __restrict__ ys,
                                               const bf16* __restrict__ kCb,
                                               const float* __restrict__ convb,
                                               const float* __restrict__ wvg,
                                               float* __restrict__ vbuf) {
  __shared__ ushort Ht[32768];  // 512 rows x 64 t, swizzled (64KB)
  const int b = blockIdx.x;
  const int tid = threadIdx.x, lane = tid & 63, w = tid >> 6;
  const int l15 = lane & 15, q = lane >> 4;
  char* HtB = (char*)Ht;

  // ---- phase 1: load ys rows (t, t+1), relu, pack u32, swizzled store ----
  for (int idx = tid; idx < 2048; idx += 256) {
    int f8 = (idx & 7) | (((idx >> 6) & 7) << 3);   // 0..63
    int t2 = ((idx >> 3) & 7) | ((idx >> 9) << 3);  // 0..31
    int t = t2 * 2;
    v8s ha = *(const v8s*)(ys + ((size_t)t * B_ + b) * HD_ + f8 * 8);
    v8s hb;
    if (t2 == 31) {
      hb = v8s{0, 0, 0, 0, 0, 0, 0, 0};  // H excludes row 63
    } else {
      hb = *(const v8s*)(ys + ((size_t)(t + 1) * B_ + b) * HD_ + f8 * 8);
    }
#pragma unroll
    for (int e = 0; e < 8; ++e) {
      ushort lo = (ha[e] & (short)0x8000) ? (ushort)0 : (ushort)ha[e];
      ushort hi = (hb[e] & (short)0x8000) ? (ushort)0 : (ushort)hb[e];
      int f = f8 * 8 + e;
      int chunk = ((t >> 3) ^ (f & 7) ^ ((f >> 3) & 7)) & 7;
      *(unsigned*)(HtB + f * 128 + chunk * 16 + (t & 7) * 2) =
          (unsigned)lo | ((unsigned)hi << 16);
    }
  }
  __syncthreads();

  // ---- phase 2: MFMA C[c][f] for f in [w*128, w*128+128) ----
  v8s af[4][2];
#pragma unroll
  for (int mi = 0; mi < 4; ++mi)
#pragma unroll
    for (int kk = 0; kk < 2; ++kk)
      af[mi][kk] = *(const v8s*)(kCb + (mi * 16 + l15) * 64 + kk * 32 + q * 8);

  v4f acc[4][8];
#pragma unroll
  for (int mi = 0; mi < 4; ++mi)
#pragma unroll
    for (int ni = 0; ni < 8; ++ni) acc[mi][ni] = v4f{0.f, 0.f, 0.f, 0.f};

#pragma unroll
  for (int ni = 0; ni < 8; ++ni) {
    const int f = w * 128 + ni * 16 + l15;
#pragma unroll
    for (int kk = 0; kk < 2; ++kk) {
      const int t0 = kk * 32 + q * 8;
      const int chunk = ((t0 >> 3) ^ (f & 7) ^ ((f >> 3) & 7)) & 7;
      v8s bf = *(const v8s*)(HtB + f * 128 + chunk * 16);
#pragma unroll
      for (int mi = 0; mi < 4; ++mi)
        acc[mi][ni] = __builtin_amdgcn_mfma_f32_16x16x32_bf16(af[mi][kk], bf, acc[mi][ni], 0, 0, 0);
    }
  }

  // ---- in-register attention ----
  // lane holds Cr at (c = mi*16 + q*4 + r, f = w*128 + ni*16 + l15)
  float cb[4][4];
#pragma unroll
  for (int mi = 0; mi < 4; ++mi)
#pragma unroll
    for (int r = 0; r < 4; ++r) cb[mi][r] = convb[mi * 16 + q * 4 + r];
  float wl[4];
#pragma unroll
  for (int nl = 0; nl < 4; ++nl) wl[nl] = wvg[(size_t)b * 64 + nl * 16 + l15];

#pragma unroll
  for (int mi = 0; mi < 4; ++mi)
#pragma unroll
    for (int ni = 0; ni < 8; ++ni)
#pragma unroll
      for (int r = 0; r < 4; ++r)
        acc[mi][ni][r] = fmaxf(acc[mi][ni][r] + cb[mi][r], 0.f);

  // s[i= c*8 + fhi] partial over l15 share, then 4x xor-reduce (j in-wave)
  float al[4][4][2];
#pragma unroll
  for (int mi = 0; mi < 4; ++mi)
#pragma unroll
    for (int r = 0; r < 4; ++r)
#pragma unroll
      for (int nh = 0; nh < 2; ++nh) {
        float s = 0.f;
#pragma unroll
        for (int nl = 0; nl < 4; ++nl)
          s += acc[mi][nh * 4 + nl][r] * wl[nl];
        s += __shfl_xor(s, 1); s += __shfl_xor(s, 2);
        s += __shfl_xor(s, 4); s += __shfl_xor(s, 8);
        al[mi][r][nh] = sigm(s);
      }

  // v[j = nl*16 + l15] partial, then xor16/32 over q (c-quarters)
  float vp[4];
#pragma unroll
  for (int nl = 0; nl < 4; ++nl) {
    float v = 0.f;
#pragma unroll
    for (int mi = 0; mi < 4; ++mi)
#pragma unroll
      for (int r = 0; r < 4; ++r)
#pragma unroll
      for (int nh = 0; nh < 2; ++nh)
        v += al[mi][r][nh] * acc[mi][nh * 4 + nl][r];
    v += __shfl_xor(v, 16);
    v += __shfl_xor(v, 32);
    vp[nl] = v;
  }
  if (lane < 16) {
#pragma unroll
    for (int nl = 0; nl < 4; ++nl)
      atomicAdd(&vbuf[(size_t)b * 64 + nl * 16 + l15], vp[nl]);
  }
}

// ---------------- epilogue: out[b] = [htt,v] . fw + fw[576] ----------------
__global__ __launch_bounds__(64) void k3_out(const bf16* __restrict__ ys,
                                             const float* __restrict__ vbuf,
                                             const float* __restrict__ fw,
                                             float* __restrict__ out) {
  const int b = blockIdx.x, tid = threadIdx.x;
  v8s h = *(const v8s*)(ys + ((size_t)(T_ - 1) * B_ + b) * HD_ + tid * 8);
  const float4 w4a = *(const float4*)(fw + tid * 8);
  const float4 w4b = *(const float4*)(fw + tid * 8 + 4);
  float a = bu2f((ushort)h[0]) * w4a.x + bu2f((ushort)h[1]) * w4a.y +
            bu2f((ushort)h[2]) * w4a.z + bu2f((ushort)h[3]) * w4a.w +
            bu2f((ushort)h[4]) * w4b.x + bu2f((ushort)h[5]) * w4b.y +
            bu2f((ushort)h[6]) * w4b.z + bu2f((ushort)h[7]) * w4b.w;
  a += vbuf[(size_t)b * 64 + tid] * fw[512 + tid];
  for (int m = 1; m < 64; m <<= 1) a += __shfl_xor(a, m);
  if (tid == 0) out[b] = a + fw[576];
}

// ---------------- launch ----------------
extern "C" void kernel_launch(void* const* d_in, const int* in_sizes, int n_in,
                              void* d_out, int out_size, void* d_ws, size_t ws_size,
                              hipStream_t stream) {
  const float* x     = (const float*)d_in[0];
  const float* Wih   = (const float*)d_in[1];
  const float* Whh   = (const float*)d_in[2];
  const float* bih   = (const float*)d_in[3];
  const float* bhh   = (const float*)d_in[4];
  const float* convW = (const float*)d_in[5];
  const float* convb = (const float*)d_in[6];
  const float* lin1W = (const float*)d_in[7];
  const float* lin1b = (const float*)d_in[8];
  const float* lin2W = (const float*)d_in[9];
  const float* lin2b = (const float*)d_in[10];
  const float* outW  = (const float*)d_in[11];
  const float* outb  = (const float*)d_in[12];

  char* ws = (char*)d_ws;
  bf16*  ys   = (bf16*)(ws + O_YS);
  bf16*  hbuf = (bf16*)(ws + O_HB);
  float* cbuf = (float*)(ws + O_CB);
  bf16*  zp   = (bf16*)(ws + O_ZP);
  float* wv   = (float*)(ws + O_WV);
  float* vbuf = (float*)(ws + O_VB);
  bf16*  Wbuf = (bf16*)(ws + O_WB);
  bf16*  kCb  = (bf16*)(ws + O_KC);
  float* fwv  = (float*)(ws + O_FW);
  bf16*  xb   = (bf16*)(ws + O_XB);

  hipMemsetAsync(hbuf, 0, SZ_HB, stream);
  hipMemsetAsync(cbuf, 0, SZ_CB, stream);
  hipMemsetAsync((void*)zp, 0, SZ_ZP, stream);
  hipMemsetAsync(vbuf, 0, SZ_VB, stream);

  prep_w<<<3072, 256, 0, stream>>>(Wih, Whh, Wbuf);
  prep_x<<<16384, 256, 0, stream>>>(x, xb);
  prep_kc<<<16, 256, 0, stream>>>(convW, kCb);
  prep_fw<<<10, 64, 0, stream>>>(lin2W, lin2b, outW, outb, fwv);

  // diagonal wavefront: stage s runs cells (l, t=s-l) for active layers
  for (int s = 0; s < T_ + 3 - 1; ++s) {
    int llo = (s > T_ - 1) ? (s - (T_ - 1)) : 0;
    int lhi = (s < 2) ? s : 2;
    int cnt = lhi - llo + 1;
    lstm_stage<<<cnt * 256, 512, 0, stream>>>(xb, Wbuf, bih, bhh, ys, hbuf,
                                              cbuf, zp, s, llo);
  }

  k0_lin1<<<B_, 64, 0, stream>>>(ys, lin1W, lin1b, wv);
  k1_attn<<<B_, 256, 0, stream>>>(ys, kCb, convb, wv, vbuf);
  k3_out<<<B_, 64, 0, stream>>>(ys, vbuf, fwv, (float*)d_out);
}